// Round 2
// baseline (418.111 us; speedup 1.0000x reference)
//
#include <hip/hip_runtime.h>
#include <hip/hip_bf16.h>

typedef unsigned short u16;
typedef __bf16 bf16x8 __attribute__((ext_vector_type(8)));
typedef float f32x4 __attribute__((ext_vector_type(4)));

#define DIM 256
#define LDK 72                       // 64 + 8 pad, keeps 16B alignment
#define BN_SCALE 0.9999950000374997f // 1/sqrt(1 + 1e-5)

__device__ __forceinline__ float bf2f(u16 u) {
    union { unsigned u; float f; } c; c.u = ((unsigned)u) << 16; return c.f;
}
__device__ __forceinline__ u16 f2bf(float f) {
    union { float f; unsigned u; } c; c.f = f;
    unsigned u = c.u;
    unsigned r = (u + 0x7FFFu + ((u >> 16) & 1u)) >> 16;  // RNE
    return (u16)r;
}
__device__ __forceinline__ float4 load_bf4(const u16* p) {
    ushort4 v = *(const ushort4*)p;
    return make_float4(bf2f(v.x), bf2f(v.y), bf2f(v.z), bf2f(v.w));
}
__device__ __forceinline__ void store_bf4(u16* p, float4 h) {
    ushort4 v; v.x = f2bf(h.x); v.y = f2bf(h.y); v.z = f2bf(h.z); v.w = f2bf(h.w);
    *(ushort4*)p = v;
}

// ---------------- dtype detection (1 wave) ----------------
// flags[0] = 1 if float tensors are bf16, 0 if fp32
// flags[1] = 1 if edge_index is int64, 0 if int32
__global__ void k_detect(const u16* __restrict__ xu, const long long* __restrict__ e64,
                         int* __restrict__ flags) {
    int lane = threadIdx.x;
    int plausible = 0;
#pragma unroll
    for (int j = 0; j < 4; ++j) {
        u16 u = xu[lane * 4 + j];
        int ex = (u >> 7) & 0xFF;
        plausible += (u == 0 || (ex >= 115 && ex <= 131)) ? 1 : 0;
    }
#pragma unroll
    for (int o = 32; o; o >>= 1) plausible += __shfl_xor(plausible, o, 64);
    long long hi = e64[lane] >> 32;
    unsigned long long b = __ballot(hi == 0);
    if (lane == 0) {
        flags[0] = (plausible >= 200) ? 1 : 0;   // bf16 arrays: ~256/256; fp32: ~135/256
        flags[1] = (b == ~0ULL) ? 1 : 0;
    }
}

// ---------------- batched convert: all float tensors -> bf16 arena ----------------
struct CvtDesc {
    const void* src[15];
    int cum[16];   // cumulative element offsets, cum[15] = total
};
__global__ void k_convert(CvtDesc d, const int* __restrict__ flags,
                          u16* __restrict__ arena, int total) {
    int i = blockIdx.x * 256 + threadIdx.x;
    if (i >= total) return;
    int t = 0;
    while (i >= d.cum[t + 1]) ++t;
    int j = i - d.cum[t];
    int isBf = flags[0];
    u16 v;
    if (isBf) v = ((const u16*)d.src[t])[j];
    else      v = f2bf(((const float*)d.src[t])[j]);
    arena[i] = v;
}

// ---------------- edge normalize + degree ----------------
__global__ void k_edges(const int* __restrict__ ei32, const int* __restrict__ flags,
                        int* __restrict__ srcN, int* __restrict__ dstN,
                        int* __restrict__ deg, int E) {
    int e = blockIdx.x * 256 + threadIdx.x;
    if (e >= E) return;
    const long long* ei64 = (const long long*)ei32;
    int w64 = flags[1];
    int s = w64 ? (int)ei64[e]     : ei32[e];
    int d = w64 ? (int)ei64[E + e] : ei32[E + e];
    srcN[e] = s; dstN[e] = d;
    atomicAdd(&deg[d], 1);
}

__global__ __launch_bounds__(1024) void k_scan(const int* __restrict__ deg,
                                               int* __restrict__ offs,
                                               int* __restrict__ cursor, int N, int E) {
    __shared__ int s[1024];
    int t = threadIdx.x;
    int P = (N + 1023) >> 10;
    int base = t * P;
    int run = 0;
    for (int j = 0; j < P; ++j) { int idx = base + j; if (idx < N) run += deg[idx]; }
    s[t] = run;
    __syncthreads();
    int total = run;
    for (int off = 1; off < 1024; off <<= 1) {
        int v = 0;
        if (t >= off) v = s[t - off];
        __syncthreads();
        if (t >= off) s[t] += v;
        __syncthreads();
    }
    int r = s[t] - total;  // exclusive prefix for this thread's chunk
    for (int j = 0; j < P; ++j) {
        int idx = base + j;
        if (idx < N) { offs[idx] = r; cursor[idx] = r; r += deg[idx]; }
    }
    if (t == 0) offs[N] = E;
}

__global__ void k_fill(const int* __restrict__ srcN, const int* __restrict__ dstN,
                       int* __restrict__ cursor, int* __restrict__ csr, int E) {
    int e = blockIdx.x * 256 + threadIdx.x;
    if (e < E) {
        int d = dstN[e];
        int pos = atomicAdd(&cursor[d], 1);
        csr[pos] = srcN[e];
    }
}

// ---------------- fused Q/K/V/Skip projection GEMM (all bf16 in, bf16 out) ----------------
__global__ __launch_bounds__(256) void gemm_qkvs(
    const u16* __restrict__ x,
    const u16* __restrict__ Wq, const u16* __restrict__ Wk,
    const u16* __restrict__ Wv, const u16* __restrict__ Ws,
    const u16* __restrict__ pbq, const u16* __restrict__ pbk,
    const u16* __restrict__ pbv, const u16* __restrict__ pbs,
    u16* __restrict__ out, int M) {
    __shared__ __align__(16) __bf16 As[64 * LDK];
    __shared__ __align__(16) __bf16 Bs[64 * LDK];
    int tid = threadIdx.x;
    int bm0 = blockIdx.x * 64;
    int bn = blockIdx.y;           // 0..15 -> virtual N tile
    int w_idx = bn >> 2;
    int n0 = (bn & 3) * 64;
    const u16* W = (w_idx == 0) ? Wq : (w_idx == 1) ? Wk : (w_idx == 2) ? Wv : Ws;
    const u16* bias = (w_idx == 0) ? pbq : (w_idx == 1) ? pbk : (w_idx == 2) ? pbv : pbs;

    int lane = tid & 63, wave = tid >> 6;
    int l15 = lane & 15, quad = lane >> 4;
    f32x4 acc[4];
#pragma unroll
    for (int nt = 0; nt < 4; ++nt) acc[nt] = (f32x4){0.f, 0.f, 0.f, 0.f};

    for (int k0 = 0; k0 < 256; k0 += 64) {
#pragma unroll
        for (int c = tid; c < 512; c += 256) {   // stage A (row-major)
            int row = c >> 3, cc = c & 7;
            int gr = bm0 + row;
            int4 val = make_int4(0, 0, 0, 0);
            if (gr < M) val = *(const int4*)(x + (size_t)gr * 256 + k0 + cc * 8);
            *(int4*)&As[row * LDK + cc * 8] = val;
        }
#pragma unroll
        for (int c = tid; c < 512; c += 256) {   // stage B transposed: Bs[n][k]
            int kk = c >> 3, nc = c & 7;
            union { int4 i4; __bf16 h[8]; } u;
            u.i4 = *(const int4*)(W + (size_t)(k0 + kk) * 256 + n0 + nc * 8);
#pragma unroll
            for (int j = 0; j < 8; ++j) Bs[(nc * 8 + j) * LDK + kk] = u.h[j];
        }
        __syncthreads();
#pragma unroll
        for (int s = 0; s < 2; ++s) {
            bf16x8 a = *(const bf16x8*)&As[(wave * 16 + l15) * LDK + s * 32 + quad * 8];
#pragma unroll
            for (int nt = 0; nt < 4; ++nt) {
                bf16x8 b = *(const bf16x8*)&Bs[(nt * 16 + l15) * LDK + s * 32 + quad * 8];
                acc[nt] = __builtin_amdgcn_mfma_f32_16x16x32_bf16(a, b, acc[nt], 0, 0, 0);
            }
        }
        __syncthreads();
    }
#pragma unroll
    for (int nt = 0; nt < 4; ++nt) {
        int colW = n0 + nt * 16 + l15;
        float bvv = bf2f(bias[colW]);
        int gcol = w_idx * 256 + colW;
#pragma unroll
        for (int r = 0; r < 4; ++r) {
            int grow = bm0 + wave * 16 + quad * 4 + r;
            if (grow < M) out[(size_t)grow * 1024 + gcol] = f2bf(acc[nt][r] + bvv);
        }
    }
}

// ---------------- fused attention (online softmax) + skip + relu ----------------
__global__ void k_attn(const u16* __restrict__ qkvs, const int* __restrict__ csr,
                       const int* __restrict__ offs, float* __restrict__ hf,
                       u16* __restrict__ hb, int N) {
    int i = blockIdx.x;
    int lane = threadIdx.x;
    size_t rowQ = (size_t)i * 1024;
    float4 q = load_bf4(qkvs + rowQ + lane * 4);
    int e0 = offs[i], e1 = offs[i + 1];
    float m = -3.4e38f;
    float denom = 0.f;
    float4 acc = make_float4(0.f, 0.f, 0.f, 0.f);
    for (int e = e0; e < e1; ++e) {
        int s = csr[e];
        const u16* kp = qkvs + (size_t)s * 1024 + 256 + lane * 4;
        float4 kk = load_bf4(kp);
        float4 vv = load_bf4(kp + 256);
        float p = q.x * kk.x + q.y * kk.y + q.z * kk.z + q.w * kk.w;
#pragma unroll
        for (int o = 32; o; o >>= 1) p += __shfl_xor(p, o, 64);
        p *= 0.0625f;  // / sqrt(256)
        float mn = fmaxf(m, p);
        float scale = __expf(m - mn);
        float w = __expf(p - mn);
        denom = denom * scale + w;
        acc.x = acc.x * scale + w * vv.x;
        acc.y = acc.y * scale + w * vv.y;
        acc.z = acc.z * scale + w * vv.z;
        acc.w = acc.w * scale + w * vv.w;
        m = mn;
    }
    float inv = (denom > 0.f) ? 1.f / denom : 0.f;
    float4 sk = load_bf4(qkvs + rowQ + 768 + lane * 4);
    float4 h;
    h.x = fmaxf(acc.x * inv + sk.x, 0.f);
    h.y = fmaxf(acc.y * inv + sk.y, 0.f);
    h.z = fmaxf(acc.z * inv + sk.z, 0.f);
    h.w = fmaxf(acc.w * inv + sk.w, 0.f);
    *(float4*)(hf + (size_t)i * 256 + lane * 4) = h;
    store_bf4(hb + (size_t)i * 256 + lane * 4, h);
}

// ---------------- SAGE mean aggregation ----------------
__global__ void k_agg(const u16* __restrict__ hin, const int* __restrict__ csr,
                      const int* __restrict__ offs, u16* __restrict__ mean_out, int N) {
    int i = blockIdx.x;
    int lane = threadIdx.x;
    int e0 = offs[i], e1 = offs[i + 1];
    float4 acc = make_float4(0.f, 0.f, 0.f, 0.f);
    for (int e = e0; e < e1; ++e) {
        int s = csr[e];
        float4 v = load_bf4(hin + (size_t)s * 256 + lane * 4);
        acc.x += v.x; acc.y += v.y; acc.z += v.z; acc.w += v.w;
    }
    int dg = e1 - e0; if (dg < 1) dg = 1;
    float inv = 1.f / (float)dg;
    acc.x *= inv; acc.y *= inv; acc.z *= inv; acc.w *= inv;
    store_bf4(mean_out + (size_t)i * 256 + lane * 4, acc);
}

// ---------------- SAGE layer GEMM + fused BN / gated residual / relu ----------------
__global__ __launch_bounds__(256) void gemm_sage(
    const u16* __restrict__ meanA, const u16* __restrict__ hA,
    const u16* __restrict__ Wl, const u16* __restrict__ Wr,
    const u16* __restrict__ bl, const u16* __restrict__ gamma,
    const u16* __restrict__ beta, const u16* __restrict__ alpha,
    float* __restrict__ hf, u16* __restrict__ hout, float* __restrict__ fout, int M) {
    __shared__ __align__(16) __bf16 As[64 * LDK];
    __shared__ __align__(16) __bf16 Bs[64 * LDK];
    int tid = threadIdx.x;
    int bm0 = blockIdx.x * 64;
    int n0 = blockIdx.y * 64;
    int lane = tid & 63, wave = tid >> 6;
    int l15 = lane & 15, quad = lane >> 4;
    f32x4 acc[4];
#pragma unroll
    for (int nt = 0; nt < 4; ++nt) acc[nt] = (f32x4){0.f, 0.f, 0.f, 0.f};

    for (int k0 = 0; k0 < 512; k0 += 64) {
        const u16* Asrc = (k0 < 256) ? meanA : hA;
        const u16* Bsrc = (k0 < 256) ? Wl : Wr;
        int kc = k0 & 255;
#pragma unroll
        for (int c = tid; c < 512; c += 256) {
            int row = c >> 3, cc = c & 7;
            int gr = bm0 + row;
            int4 val = make_int4(0, 0, 0, 0);
            if (gr < M) val = *(const int4*)(Asrc + (size_t)gr * 256 + kc + cc * 8);
            *(int4*)&As[row * LDK + cc * 8] = val;
        }
#pragma unroll
        for (int c = tid; c < 512; c += 256) {
            int kk = c >> 3, nc = c & 7;
            union { int4 i4; __bf16 h[8]; } u;
            u.i4 = *(const int4*)(Bsrc + (size_t)(kc + kk) * 256 + n0 + nc * 8);
#pragma unroll
            for (int j = 0; j < 8; ++j) Bs[(nc * 8 + j) * LDK + kk] = u.h[j];
        }
        __syncthreads();
#pragma unroll
        for (int s = 0; s < 2; ++s) {
            bf16x8 a = *(const bf16x8*)&As[(wave * 16 + l15) * LDK + s * 32 + quad * 8];
#pragma unroll
            for (int nt = 0; nt < 4; ++nt) {
                bf16x8 b = *(const bf16x8*)&Bs[(nt * 16 + l15) * LDK + s * 32 + quad * 8];
                acc[nt] = __builtin_amdgcn_mfma_f32_16x16x32_bf16(a, b, acc[nt], 0, 0, 0);
            }
        }
        __syncthreads();
    }

    float aval = bf2f(alpha[0]);
    float al = 1.f / (1.f + __expf(-aval));
    float alc = 1.f - al;
#pragma unroll
    for (int nt = 0; nt < 4; ++nt) {
        int n = n0 + nt * 16 + l15;
        float g = bf2f(gamma[n]) * BN_SCALE;
        float be = bf2f(beta[n]);
        float bb = bf2f(bl[n]);
#pragma unroll
        for (int r = 0; r < 4; ++r) {
            int grow = bm0 + wave * 16 + quad * 4 + r;
            if (grow < M) {
                size_t idx = (size_t)grow * 256 + n;
                float z = acc[nt][r] + bb;
                z = z * g + be;
                float prev = hf[idx];
                z = al * z + alc * prev;
                z = fmaxf(z, 0.f);
                hf[idx] = z;         // in-place f32 residual (same-thread RAW only)
                hout[idx] = f2bf(z);
                if (fout) fout[idx] = z;
            }
        }
    }
}

extern "C" void kernel_launch(void* const* d_in, const int* in_sizes, int n_in,
                              void* d_out, int out_size, void* d_ws, size_t ws_size,
                              hipStream_t stream) {
    int N = in_sizes[0] / DIM;
    int E = in_sizes[1] / 2;
    int L = in_sizes[10] / (DIM * DIM);

    // ---- build convert descriptor: order x,Wq,Wk,Wv,Ws,Wl,Wr,bq,bk,bv,bs,bl,gamma,beta,alpha
    const int map[15] = {0, 2, 4, 6, 8, 10, 12, 3, 5, 7, 9, 11, 13, 14, 15};
    CvtDesc cd;
    cd.cum[0] = 0;
    for (int t = 0; t < 15; ++t) {
        cd.src[t] = d_in[map[t]];
        cd.cum[t + 1] = cd.cum[t] + in_sizes[map[t]];
    }
    int total = cd.cum[15];

    char* ws = (char*)d_ws;
    size_t off = 0;
    auto take = [&](size_t bytes) { size_t c = off; off = (off + bytes + 15) & ~15ULL; return c; };

    int* flags  = (int*)(ws + take(16));
    u16* arena  = (u16*)(ws + take((size_t)total * 2));
    int* srcN   = (int*)(ws + take((size_t)E * 4));
    int* dstN   = (int*)(ws + take((size_t)E * 4));
    int* csr    = (int*)(ws + take((size_t)E * 4));
    int* deg    = (int*)(ws + take((size_t)N * 4));
    int* offs   = (int*)(ws + take((size_t)(N + 1) * 4));
    int* cursor = (int*)(ws + take((size_t)N * 4));
    float* hF   = (float*)(ws + take((size_t)N * DIM * 4));
    u16* hB0    = (u16*)(ws + take((size_t)N * DIM * 2));
    u16* qkvsB  = (u16*)(ws + take((size_t)N * 1024 * 2)); // dead after k_attn
    u16* meanB  = qkvsB;                                   // overlay
    u16* hB1    = qkvsB + (size_t)N * DIM;                 // overlay
    (void)ws_size; (void)n_in; (void)out_size;

    const u16* xb  = arena + cd.cum[0];
    const u16* Wqb = arena + cd.cum[1];
    const u16* Wkb = arena + cd.cum[2];
    const u16* Wvb = arena + cd.cum[3];
    const u16* Wsb = arena + cd.cum[4];
    const u16* Wlb = arena + cd.cum[5];
    const u16* Wrb = arena + cd.cum[6];
    const u16* bqb = arena + cd.cum[7];
    const u16* bkb = arena + cd.cum[8];
    const u16* bvb = arena + cd.cum[9];
    const u16* bsb = arena + cd.cum[10];
    const u16* blb = arena + cd.cum[11];
    const u16* gmb = arena + cd.cum[12];
    const u16* btb = arena + cd.cum[13];
    const u16* alb = arena + cd.cum[14];

    k_detect<<<1, 64, 0, stream>>>((const u16*)d_in[0], (const long long*)d_in[1], flags);
    k_convert<<<(total + 255) / 256, 256, 0, stream>>>(cd, flags, arena, total);

    hipMemsetAsync(deg, 0, (size_t)N * 4, stream);
    int eb = (E + 255) / 256;
    k_edges<<<eb, 256, 0, stream>>>((const int*)d_in[1], flags, srcN, dstN, deg, E);
    k_scan<<<1, 1024, 0, stream>>>(deg, offs, cursor, N, E);
    k_fill<<<eb, 256, 0, stream>>>(srcN, dstN, cursor, csr, E);

    int Mb = (N + 63) / 64;
    gemm_qkvs<<<dim3(Mb, 16), 256, 0, stream>>>(xb, Wqb, Wkb, Wvb, Wsb,
                                                bqb, bkb, bvb, bsb, qkvsB, N);
    k_attn<<<N, 64, 0, stream>>>(qkvsB, csr, offs, hF, hB0, N);

    for (int l = 0; l < L; ++l) {
        const u16* hin = (l & 1) ? hB1 : hB0;
        u16* hout      = (l & 1) ? hB0 : hB1;
        float* fout = (l == L - 1) ? (float*)d_out : nullptr;
        k_agg<<<N, 64, 0, stream>>>(hin, csr, offs, meanB, N);
        gemm_sage<<<dim3(Mb, 4), 256, 0, stream>>>(
            meanB, hin, Wlb + (size_t)l * DIM * DIM, Wrb + (size_t)l * DIM * DIM,
            blb + (size_t)l * DIM, gmb + (size_t)l * DIM, btb + (size_t)l * DIM,
            alb, hF, hout, fout, N);
    }
}

// Round 3
// 317.633 us; speedup vs baseline: 1.3163x; 1.3163x over previous
//
#include <hip/hip_runtime.h>
#include <hip/hip_bf16.h>

typedef unsigned short u16;
typedef unsigned int u32;
typedef __bf16 bf16x8 __attribute__((ext_vector_type(8)));
typedef float f32x4 __attribute__((ext_vector_type(4)));

#define DIM 256
#define BN_SCALE 0.9999950000374997f // 1/sqrt(1 + 1e-5)

__device__ __forceinline__ float bf2f(u16 u) {
    union { unsigned u; float f; } c; c.u = ((unsigned)u) << 16; return c.f;
}
__device__ __forceinline__ u16 f2bf(float f) {
    union { float f; unsigned u; } c; c.f = f;
    unsigned u = c.u;
    unsigned r = (u + 0x7FFFu + ((u >> 16) & 1u)) >> 16;  // RNE
    return (u16)r;
}
__device__ __forceinline__ float asf(unsigned u) {
    union { unsigned u; float f; } c; c.u = u; return c.f;
}
// 8 bf16 packed in int4 -> 8 f32 (2 bit-ops per dword, no cvt chain)
__device__ __forceinline__ void cvt8(int4 v, float* f) {
    unsigned a0 = (unsigned)v.x, a1 = (unsigned)v.y, a2 = (unsigned)v.z, a3 = (unsigned)v.w;
    f[0] = asf(a0 << 16); f[1] = asf(a0 & 0xFFFF0000u);
    f[2] = asf(a1 << 16); f[3] = asf(a1 & 0xFFFF0000u);
    f[4] = asf(a2 << 16); f[5] = asf(a2 & 0xFFFF0000u);
    f[6] = asf(a3 << 16); f[7] = asf(a3 & 0xFFFF0000u);
}
__device__ __forceinline__ float dot8(const float* a, const float* b) {
    float s = a[0] * b[0];
    s += a[1] * b[1]; s += a[2] * b[2]; s += a[3] * b[3];
    s += a[4] * b[4]; s += a[5] * b[5]; s += a[6] * b[6]; s += a[7] * b[7];
    return s;
}
// async global->LDS, 16B per lane; lds base must be wave-uniform
__device__ __forceinline__ void gl_lds16(const u16* g, u16* l) {
    __builtin_amdgcn_global_load_lds(
        (__attribute__((address_space(1))) const u32*)(const void*)g,
        (__attribute__((address_space(3))) u32*)(void*)l, 16, 0, 0);
}

// ---------------- dtype detection (1 wave) ----------------
__global__ void k_detect(const u16* __restrict__ xu, const long long* __restrict__ e64,
                         int* __restrict__ flags) {
    int lane = threadIdx.x;
    int plausible = 0;
#pragma unroll
    for (int j = 0; j < 4; ++j) {
        u16 u = xu[lane * 4 + j];
        int ex = (u >> 7) & 0xFF;
        plausible += (u == 0 || (ex >= 115 && ex <= 131)) ? 1 : 0;
    }
#pragma unroll
    for (int o = 32; o; o >>= 1) plausible += __shfl_xor(plausible, o, 64);
    long long hi = e64[lane] >> 32;
    unsigned long long b = __ballot(hi == 0);
    if (lane == 0) {
        flags[0] = (plausible >= 200) ? 1 : 0;
        flags[1] = (b == ~0ULL) ? 1 : 0;
    }
}

// ---------------- batched convert: all float tensors -> bf16 arena ----------------
struct CvtDesc {
    const void* src[15];
    int cum[16];
};
__global__ void k_convert(CvtDesc d, const int* __restrict__ flags,
                          u16* __restrict__ arena, int total) {
    int i = blockIdx.x * 256 + threadIdx.x;
    if (i >= total) return;
    int t = 0;
    while (i >= d.cum[t + 1]) ++t;
    int j = i - d.cum[t];
    u16 v;
    if (flags[0]) v = ((const u16*)d.src[t])[j];
    else          v = f2bf(((const float*)d.src[t])[j]);
    arena[i] = v;
}

// ---------------- transpose 256x256 bf16 matrices (for global_load_lds B staging) ----------------
struct TDesc { const u16* src[12]; u16* dst[12]; };
__global__ __launch_bounds__(256) void k_transpose(TDesc td) {
    __shared__ u16 t[64][72];
    int m = blockIdx.x >> 4, tl = blockIdx.x & 15;
    int tr = (tl >> 2) * 64, tc = (tl & 3) * 64;
    const u16* S = td.src[m];
    u16* D = td.dst[m];
    int r = threadIdx.x >> 2, cs = (threadIdx.x & 3) * 16;
    *(int4*)&t[r][cs]     = *(const int4*)&S[(tr + r) * 256 + tc + cs];
    *(int4*)&t[r][cs + 8] = *(const int4*)&S[(tr + r) * 256 + tc + cs + 8];
    __syncthreads();
    u16 tmp[16];
#pragma unroll
    for (int j = 0; j < 16; ++j) tmp[j] = t[cs + j][r];
    *(int4*)&D[(tc + r) * 256 + tr + cs]     = *(int4*)&tmp[0];
    *(int4*)&D[(tc + r) * 256 + tr + cs + 8] = *(int4*)&tmp[8];
}

// ---------------- edge normalize + degree ----------------
__global__ void k_edges(const int* __restrict__ ei32, const int* __restrict__ flags,
                        int* __restrict__ srcN, int* __restrict__ dstN,
                        int* __restrict__ deg, int E) {
    int e = blockIdx.x * 256 + threadIdx.x;
    if (e >= E) return;
    const long long* ei64 = (const long long*)ei32;
    int w64 = flags[1];
    int s = w64 ? (int)ei64[e]     : ei32[e];
    int d = w64 ? (int)ei64[E + e] : ei32[E + e];
    srcN[e] = s; dstN[e] = d;
    atomicAdd(&deg[d], 1);
}

__global__ __launch_bounds__(1024) void k_scan(const int* __restrict__ deg,
                                               int* __restrict__ offs,
                                               int* __restrict__ cursor, int N, int E) {
    __shared__ int s[1024];
    int t = threadIdx.x;
    int P = (N + 1023) >> 10;
    int base = t * P;
    int run = 0;
    for (int j = 0; j < P; ++j) { int idx = base + j; if (idx < N) run += deg[idx]; }
    s[t] = run;
    __syncthreads();
    int total = run;
    for (int off = 1; off < 1024; off <<= 1) {
        int v = 0;
        if (t >= off) v = s[t - off];
        __syncthreads();
        if (t >= off) s[t] += v;
        __syncthreads();
    }
    int r = s[t] - total;
    for (int j = 0; j < P; ++j) {
        int idx = base + j;
        if (idx < N) { offs[idx] = r; cursor[idx] = r; r += deg[idx]; }
    }
    if (t == 0) offs[N] = E;
}

__global__ void k_fill(const int* __restrict__ srcN, const int* __restrict__ dstN,
                       int* __restrict__ cursor, int* __restrict__ csr, int E) {
    int e = blockIdx.x * 256 + threadIdx.x;
    if (e < E) {
        int d = dstN[e];
        int pos = atomicAdd(&cursor[d], 1);
        csr[pos] = srcN[e];
    }
}

// ---------------- fused QKVS GEMM: out[M x 1024] = x @ WT^T + bias ----------------
// WT is [1024][256] (n-major, pre-transposed), bias is fused 1024.
__global__ __launch_bounds__(256) void gemm_qkvs(
    const u16* __restrict__ x, const u16* __restrict__ WT,
    const u16* __restrict__ bias, u16* __restrict__ out, int M) {
    __shared__ __align__(16) u16 lds[16384];       // As [0,8192) 128x64; Bs [8192,16384) 128x64
    u16* As = lds;
    u16* Bs = lds + 8192;
    int tid = threadIdx.x, w = tid >> 6, lane = tid & 63;
    int l15 = lane & 15, quad = lane >> 4;
    int lr = lane >> 3, lc = lane & 7;
    int bm0 = blockIdx.x * 128, bn0 = blockIdx.y * 128;
    f32x4 acc[4][4];
#pragma unroll
    for (int a = 0; a < 4; ++a)
#pragma unroll
        for (int b = 0; b < 4; ++b) acc[a][b] = (f32x4){0.f, 0.f, 0.f, 0.f};

    for (int k0 = 0; k0 < 256; k0 += 64) {
#pragma unroll
        for (int j = 0; j < 4; ++j) {
            int ar = (w * 4 + j) * 8 + lr;
            int grow = bm0 + ar; if (grow >= M) grow = M - 1;
            gl_lds16(x + (size_t)grow * 256 + k0 + lc * 8, &As[(w * 4 + j) * 512]);
        }
#pragma unroll
        for (int j = 0; j < 4; ++j) {
            int nr = (w * 4 + j) * 8 + lr;
            gl_lds16(WT + (size_t)(bn0 + nr) * 256 + k0 + lc * 8, &Bs[(w * 4 + j) * 512]);
        }
        __syncthreads();
        int wm = w & 1, wn = w >> 1;
#pragma unroll
        for (int s = 0; s < 2; ++s) {
            bf16x8 a[4], b[4];
#pragma unroll
            for (int t = 0; t < 4; ++t)
                a[t] = *(const bf16x8*)&As[(wm * 64 + t * 16 + l15) * 64 + s * 32 + quad * 8];
#pragma unroll
            for (int t = 0; t < 4; ++t)
                b[t] = *(const bf16x8*)&Bs[(wn * 64 + t * 16 + l15) * 64 + s * 32 + quad * 8];
#pragma unroll
            for (int rt = 0; rt < 4; ++rt)
#pragma unroll
                for (int ct = 0; ct < 4; ++ct)
                    acc[rt][ct] = __builtin_amdgcn_mfma_f32_16x16x32_bf16(a[rt], b[ct], acc[rt][ct], 0, 0, 0);
        }
        __syncthreads();
    }
    // epilogue: +bias, bf16, LDS round-trip for coalesced stores
    int wm = w & 1, wn = w >> 1;
    u16* oL = lds + w * 4096;                     // 64x64 per wave
#pragma unroll
    for (int rt = 0; rt < 4; ++rt)
#pragma unroll
        for (int ct = 0; ct < 4; ++ct) {
            int col = bn0 + wn * 64 + ct * 16 + l15;
            float bv = bf2f(bias[col]);
#pragma unroll
            for (int r = 0; r < 4; ++r)
                oL[(rt * 16 + quad * 4 + r) * 64 + ct * 16 + l15] = f2bf(acc[rt][ct][r] + bv);
        }
    __syncthreads();
#pragma unroll
    for (int j = 0; j < 8; ++j) {
        int orow = j * 8 + lr;
        int grow = bm0 + wm * 64 + orow;
        if (grow < M)
            *(int4*)&out[(size_t)grow * 1024 + bn0 + wn * 64 + lc * 8] = *(const int4*)&oL[orow * 64 + lc * 8];
    }
}

// ---------------- fused attention: online softmax + skip + relu, K/V split across wave ----------------
__global__ __launch_bounds__(256) void k_attn(const u16* __restrict__ qkvs,
                                              const int* __restrict__ csr,
                                              const int* __restrict__ offs,
                                              u16* __restrict__ hb, int N) {
    int wv = threadIdx.x >> 6, lane = threadIdx.x & 63;
    int i = blockIdx.x * 4 + wv;
    if (i >= N) return;
    size_t row = (size_t)i * 1024;
    int up = lane >> 5;      // lanes 0-31: K dims; 32-63: V dims
    int hl = lane & 31;
    float qf[8];
#pragma unroll
    for (int d = 0; d < 8; ++d) qf[d] = 0.f;
    if (!up) {
        int4 qv = *(const int4*)(qkvs + row + (unsigned)lane * 8);
        cvt8(qv, qf);
#pragma unroll
        for (int d = 0; d < 8; ++d) qf[d] *= 0.0625f;   // fold 1/sqrt(256)
    }
    int e0 = offs[i], e1 = offs[i + 1];
    float m = -1e30f, denom = 0.f;
    float acc[8];
#pragma unroll
    for (int d = 0; d < 8; ++d) acc[d] = 0.f;

    const u16* base = qkvs + 256 + (unsigned)lane * 8;  // covers K (lower) and V (upper)
    int e = e0;
    for (; e + 4 <= e1; e += 4) {
        int s0 = csr[e], s1 = csr[e + 1], s2 = csr[e + 2], s3 = csr[e + 3];
        int4 r0 = *(const int4*)(base + (size_t)s0 * 1024);
        int4 r1 = *(const int4*)(base + (size_t)s1 * 1024);
        int4 r2 = *(const int4*)(base + (size_t)s2 * 1024);
        int4 r3 = *(const int4*)(base + (size_t)s3 * 1024);
        float f0[8], f1[8], f2[8], f3[8];
        cvt8(r0, f0); cvt8(r1, f1); cvt8(r2, f2); cvt8(r3, f3);
        float p0 = dot8(qf, f0), p1 = dot8(qf, f1), p2 = dot8(qf, f2), p3 = dot8(qf, f3);
#pragma unroll
        for (int o = 32; o; o >>= 1) {
            p0 += __shfl_xor(p0, o, 64);
            p1 += __shfl_xor(p1, o, 64);
            p2 += __shfl_xor(p2, o, 64);
            p3 += __shfl_xor(p3, o, 64);
        }
        float pm = fmaxf(fmaxf(p0, p1), fmaxf(p2, p3));
        if (pm > m) {                      // wave-uniform branch
            float sc = __expf(m - pm);
            denom *= sc;
#pragma unroll
            for (int d = 0; d < 8; ++d) acc[d] *= sc;
            m = pm;
        }
        float w0 = __expf(p0 - m), w1 = __expf(p1 - m), w2 = __expf(p2 - m), w3 = __expf(p3 - m);
        denom += (w0 + w1) + (w2 + w3);
#pragma unroll
        for (int d = 0; d < 8; ++d)
            acc[d] += (w0 * f0[d] + w1 * f1[d]) + (w2 * f2[d] + w3 * f3[d]);
    }
    for (; e < e1; ++e) {
        int s0 = csr[e];
        int4 r0 = *(const int4*)(base + (size_t)s0 * 1024);
        float f0[8];
        cvt8(r0, f0);
        float p0 = dot8(qf, f0);
#pragma unroll
        for (int o = 32; o; o >>= 1) p0 += __shfl_xor(p0, o, 64);
        if (p0 > m) {
            float sc = __expf(m - p0);
            denom *= sc;
#pragma unroll
            for (int d = 0; d < 8; ++d) acc[d] *= sc;
            m = p0;
        }
        float w0 = __expf(p0 - m);
        denom += w0;
#pragma unroll
        for (int d = 0; d < 8; ++d) acc[d] += w0 * f0[d];
    }
    float inv = (denom > 0.f) ? 1.f / denom : 0.f;
    if (up) {
        int4 skv = *(const int4*)(qkvs + row + 768 + (unsigned)hl * 8);
        float sk[8];
        cvt8(skv, sk);
        u16 o16[8];
#pragma unroll
        for (int d = 0; d < 8; ++d) {
            float h = fmaxf(acc[d] * inv + sk[d], 0.f);
            o16[d] = f2bf(h);
        }
        *(int4*)(hb + (size_t)i * 256 + (unsigned)hl * 8) = *(const int4*)o16;
    }
}

// ---------------- SAGE mean aggregation: 8 nodes per 256-thr block, 32 lanes/node ----------------
__global__ __launch_bounds__(256) void k_agg(const u16* __restrict__ hin,
                                             const int* __restrict__ csr,
                                             const int* __restrict__ offs,
                                             u16* __restrict__ mean_out, int N) {
    int half = threadIdx.x >> 5, hl = threadIdx.x & 31;
    int i = blockIdx.x * 8 + half;
    if (i >= N) return;
    int e0 = offs[i], e1 = offs[i + 1];
    const u16* base = hin + (unsigned)hl * 8;
    float acc[8];
#pragma unroll
    for (int d = 0; d < 8; ++d) acc[d] = 0.f;
    int e = e0;
    for (; e + 4 <= e1; e += 4) {
        int s0 = csr[e], s1 = csr[e + 1], s2 = csr[e + 2], s3 = csr[e + 3];
        int4 r0 = *(const int4*)(base + (size_t)s0 * 256);
        int4 r1 = *(const int4*)(base + (size_t)s1 * 256);
        int4 r2 = *(const int4*)(base + (size_t)s2 * 256);
        int4 r3 = *(const int4*)(base + (size_t)s3 * 256);
        float f0[8], f1[8], f2[8], f3[8];
        cvt8(r0, f0); cvt8(r1, f1); cvt8(r2, f2); cvt8(r3, f3);
#pragma unroll
        for (int d = 0; d < 8; ++d) acc[d] += (f0[d] + f1[d]) + (f2[d] + f3[d]);
    }
    for (; e < e1; ++e) {
        int s0 = csr[e];
        int4 r0 = *(const int4*)(base + (size_t)s0 * 256);
        float f0[8];
        cvt8(r0, f0);
#pragma unroll
        for (int d = 0; d < 8; ++d) acc[d] += f0[d];
    }
    int dg = e1 - e0; if (dg < 1) dg = 1;
    float inv = 1.f / (float)dg;
    u16 o16[8];
#pragma unroll
    for (int d = 0; d < 8; ++d) o16[d] = f2bf(acc[d] * inv);
    *(int4*)(mean_out + (size_t)i * 256 + (unsigned)hl * 8) = *(const int4*)o16;
}

// ---------------- SAGE GEMM (K=512 concat) + fused BN / gated residual / relu ----------------
// WlT/WrT: [256][256] n-major. 128(M) x 64(N) tile, 4 waves each 32x64.
__global__ __launch_bounds__(256) void gemm_sage(
    const u16* __restrict__ meanA, const u16* __restrict__ hin,
    const u16* __restrict__ WlT, const u16* __restrict__ WrT,
    const u16* __restrict__ bl, const u16* __restrict__ gamma,
    const u16* __restrict__ beta, const u16* __restrict__ alpha,
    u16* __restrict__ hout, float* __restrict__ fout, int M) {
    __shared__ __align__(16) u16 lds[12288];     // As [0,8192) 128x64; Bs [8192,12288) 64x64
    u16* As = lds;
    u16* Bs = lds + 8192;
    int tid = threadIdx.x, w = tid >> 6, lane = tid & 63;
    int l15 = lane & 15, quad = lane >> 4;
    int lr = lane >> 3, lc = lane & 7;
    int bm0 = blockIdx.x * 128, n0 = blockIdx.y * 64;
    f32x4 acc[2][4];
#pragma unroll
    for (int a = 0; a < 2; ++a)
#pragma unroll
        for (int b = 0; b < 4; ++b) acc[a][b] = (f32x4){0.f, 0.f, 0.f, 0.f};

    for (int k0 = 0; k0 < 512; k0 += 64) {
        const u16* Asrc = (k0 < 256) ? meanA : hin;
        const u16* Bsrc = (k0 < 256) ? WlT : WrT;
        int kc = k0 & 255;
#pragma unroll
        for (int j = 0; j < 4; ++j) {
            int ar = (w * 4 + j) * 8 + lr;
            int grow = bm0 + ar; if (grow >= M) grow = M - 1;
            gl_lds16(Asrc + (size_t)grow * 256 + kc + lc * 8, &As[(w * 4 + j) * 512]);
        }
#pragma unroll
        for (int j = 0; j < 2; ++j) {
            int nr = (w * 2 + j) * 8 + lr;
            gl_lds16(Bsrc + (size_t)(n0 + nr) * 256 + kc + lc * 8, &Bs[(w * 2 + j) * 512]);
        }
        __syncthreads();
#pragma unroll
        for (int s = 0; s < 2; ++s) {
            bf16x8 a[2], b[4];
#pragma unroll
            for (int t = 0; t < 2; ++t)
                a[t] = *(const bf16x8*)&As[(w * 32 + t * 16 + l15) * 64 + s * 32 + quad * 8];
#pragma unroll
            for (int t = 0; t < 4; ++t)
                b[t] = *(const bf16x8*)&Bs[(t * 16 + l15) * 64 + s * 32 + quad * 8];
#pragma unroll
            for (int rt = 0; rt < 2; ++rt)
#pragma unroll
                for (int ct = 0; ct < 4; ++ct)
                    acc[rt][ct] = __builtin_amdgcn_mfma_f32_16x16x32_bf16(a[rt], b[ct], acc[rt][ct], 0, 0, 0);
        }
        __syncthreads();
    }

    float al = 1.f / (1.f + __expf(-bf2f(alpha[0])));
    float alc = 1.f - al;
    u16* oL = lds + w * 2048;                   // 32x64 per wave
#pragma unroll
    for (int rt = 0; rt < 2; ++rt)
#pragma unroll
        for (int ct = 0; ct < 4; ++ct) {
            int col = n0 + ct * 16 + l15;
            float g  = bf2f(gamma[col]) * BN_SCALE;
            float be = bf2f(beta[col]);
            float bb = bf2f(bl[col]);
#pragma unroll
            for (int r = 0; r < 4; ++r) {
                int grow = bm0 + w * 32 + rt * 16 + quad * 4 + r;
                float z = (acc[rt][ct][r] + bb) * g + be;
                float prev = (grow < M) ? bf2f(hin[(size_t)grow * 256 + col]) : 0.f;
                z = al * z + alc * prev;
                z = fmaxf(z, 0.f);
                oL[(rt * 16 + quad * 4 + r) * 64 + ct * 16 + l15] = f2bf(z);
                if (fout && grow < M) fout[(size_t)grow * 256 + col] = z;
            }
        }
    __syncthreads();
#pragma unroll
    for (int j = 0; j < 4; ++j) {
        int orow = j * 8 + lr;                  // 0..31
        int grow = bm0 + w * 32 + orow;
        if (grow < M)
            *(int4*)&hout[(size_t)grow * 256 + n0 + lc * 8] = *(const int4*)&oL[orow * 64 + lc * 8];
    }
}

extern "C" void kernel_launch(void* const* d_in, const int* in_sizes, int n_in,
                              void* d_out, int out_size, void* d_ws, size_t ws_size,
                              hipStream_t stream) {
    int N = in_sizes[0] / DIM;
    int E = in_sizes[1] / 2;
    int L = in_sizes[10] / (DIM * DIM);

    // arena order: x,Wq,Wk,Wv,Ws,Wl,Wr,bq,bk,bv,bs,bl,gamma,beta,alpha
    const int map[15] = {0, 2, 4, 6, 8, 10, 12, 3, 5, 7, 9, 11, 13, 14, 15};
    CvtDesc cd;
    cd.cum[0] = 0;
    for (int t = 0; t < 15; ++t) {
        cd.src[t] = d_in[map[t]];
        cd.cum[t + 1] = cd.cum[t] + in_sizes[map[t]];
    }
    int total = cd.cum[15];

    char* ws = (char*)d_ws;
    size_t off = 0;
    auto take = [&](size_t bytes) { size_t c = off; off = (off + bytes + 255) & ~255ULL; return c; };

    int* flags  = (int*)(ws + take(16));
    u16* arena  = (u16*)(ws + take((size_t)total * 2));
    u16* WT     = (u16*)(ws + take((size_t)(4 + 2 * L) * DIM * DIM * 2));
    int* srcN   = (int*)(ws + take((size_t)E * 4));
    int* dstN   = (int*)(ws + take((size_t)E * 4));
    int* csr    = (int*)(ws + take((size_t)E * 4));
    int* deg    = (int*)(ws + take((size_t)N * 4));
    int* offs   = (int*)(ws + take((size_t)(N + 1) * 4));
    int* cursor = (int*)(ws + take((size_t)N * 4));
    u16* hB0    = (u16*)(ws + take((size_t)N * DIM * 2));
    u16* qkvsB  = (u16*)(ws + take((size_t)N * 1024 * 2)); // dead after k_attn
    u16* meanB  = qkvsB;                                   // overlay
    u16* hB1    = qkvsB + (size_t)N * DIM;                 // overlay
    (void)ws_size; (void)n_in; (void)out_size;

    const u16* xb  = arena + cd.cum[0];
    const u16* Wqb = arena + cd.cum[1];
    const u16* Wkb = arena + cd.cum[2];
    const u16* Wvb = arena + cd.cum[3];
    const u16* Wsb = arena + cd.cum[4];
    const u16* Wlb = arena + cd.cum[5];
    const u16* Wrb = arena + cd.cum[6];
    const u16* biasF = arena + cd.cum[7];   // bq|bk|bv|bs contiguous = fused 1024
    const u16* blb = arena + cd.cum[11];
    const u16* gmb = arena + cd.cum[12];
    const u16* btb = arena + cd.cum[13];
    const u16* alb = arena + cd.cum[14];

    k_detect<<<1, 64, 0, stream>>>((const u16*)d_in[0], (const long long*)d_in[1], flags);
    k_convert<<<(total + 255) / 256, 256, 0, stream>>>(cd, flags, arena, total);

    // transposes: WT layout [Wq|Wk|Wv|Ws | Wl0..L-1 | Wr0..L-1], each [256][256] n-major
    TDesc td;
    int nMat = 0;
    const u16* wsrc[4] = {Wqb, Wkb, Wvb, Wsb};
    for (int t = 0; t < 4; ++t) { td.src[nMat] = wsrc[t]; td.dst[nMat] = WT + (size_t)nMat * DIM * DIM; ++nMat; }
    for (int l = 0; l < L; ++l) { td.src[nMat] = Wlb + (size_t)l * DIM * DIM; td.dst[nMat] = WT + (size_t)nMat * DIM * DIM; ++nMat; }
    for (int l = 0; l < L; ++l) { td.src[nMat] = Wrb + (size_t)l * DIM * DIM; td.dst[nMat] = WT + (size_t)nMat * DIM * DIM; ++nMat; }
    k_transpose<<<nMat * 16, 256, 0, stream>>>(td);

    hipMemsetAsync(deg, 0, (size_t)N * 4, stream);
    int eb = (E + 255) / 256;
    k_edges<<<eb, 256, 0, stream>>>((const int*)d_in[1], flags, srcN, dstN, deg, E);
    k_scan<<<1, 1024, 0, stream>>>(deg, offs, cursor, N, E);
    k_fill<<<eb, 256, 0, stream>>>(srcN, dstN, cursor, csr, E);

    int Mb128 = (N + 127) / 128;
    gemm_qkvs<<<dim3(Mb128, 8), 256, 0, stream>>>(xb, WT, biasF, qkvsB, N);
    k_attn<<<(N + 3) / 4, 256, 0, stream>>>(qkvsB, csr, offs, hB0, N);

    for (int l = 0; l < L; ++l) {
        const u16* hin = (l & 1) ? hB1 : hB0;
        u16* hout      = (l & 1) ? hB0 : hB1;
        float* fout = (l == L - 1) ? (float*)d_out : nullptr;
        k_agg<<<(N + 7) / 8, 256, 0, stream>>>(hin, csr, offs, meanB, N);
        gemm_sage<<<dim3(Mb128, 4), 256, 0, stream>>>(
            meanB, hin, WT + (size_t)(4 + l) * DIM * DIM, WT + (size_t)(4 + L + l) * DIM * DIM,
            blb + (size_t)l * DIM, gmb + (size_t)l * DIM, btb + (size_t)l * DIM,
            alb, hout, fout, N);
    }
}